// Round 1
// baseline (72.456 us; speedup 1.0000x reference)
//
#include <hip/hip_runtime.h>
#include <math.h>

#define Bb   2
#define Vv   20000
#define Cc   9
#define KS   9
#define OUTn 16
#define NB   16

__global__ __launch_bounds__(256) void nlayer_kernel(
    const float* __restrict__ x,   // (B,V,C)
    const float* __restrict__ W,   // (C,KS,OUT)
    const int*   __restrict__ adj, // (V,NB)
    float* __restrict__ out)       // (B,V,OUT)
{
    __shared__ float sW[Cc * KS * OUTn];   // 1296 floats = 5184 B
    for (int i = threadIdx.x; i < Cc * KS * OUTn; i += 256) sW[i] = W[i];
    __syncthreads();

    int tid = blockIdx.x * 256 + threadIdx.x;
    if (tid >= Bb * Vv) return;
    int b = tid / Vv;
    int v = tid - b * Vv;

    // adj row (16 ints)
    int a[NB];
    #pragma unroll
    for (int n = 0; n < NB; ++n) a[n] = adj[v * NB + n];

    int deg = 0;
    #pragma unroll
    for (int n = 0; n < NB; ++n) deg += (a[n] != 0);

    const float* xb = x + (size_t)b * Vv * Cc;

    float xv[Cc];
    #pragma unroll
    for (int c = 0; c < Cc; ++c) xv[c] = xb[(size_t)v * Cc + c];

    // s[k][c] = sum_n q[n,k] * xn[n,c]
    float s[KS][Cc];
    #pragma unroll
    for (int k = 0; k < KS; ++k)
        #pragma unroll
        for (int c = 0; c < Cc; ++c) s[k][c] = 0.0f;

    for (int n = 0; n < NB; ++n) {
        int j = a[n];
        if (j == 0) continue;          // masked: xn=0 -> patches=0 -> no contribution
        const float* xp = xb + (size_t)(j - 1) * Cc;
        float xn[Cc];
        #pragma unroll
        for (int c = 0; c < Cc; ++c) xn[c] = xp[c];

        float d[Cc];
        float m = -INFINITY;
        #pragma unroll
        for (int c = 0; c < Cc; ++c) { d[c] = xv[c] - xn[c]; m = fmaxf(m, d[c]); }
        float e[Cc];
        float sum = 0.0f;
        #pragma unroll
        for (int c = 0; c < Cc; ++c) { e[c] = __expf(d[c] - m); sum += e[c]; }
        float inv = 1.0f / sum;

        #pragma unroll
        for (int k = 0; k < KS; ++k) {
            float qk = e[k] * inv;
            #pragma unroll
            for (int c = 0; c < Cc; ++c) s[k][c] = fmaf(qk, xn[c], s[k][c]);
        }
    }

    float invdeg = (deg > 0) ? (1.0f / (float)deg) : 0.0f;

    float acc[OUTn];
    #pragma unroll
    for (int o = 0; o < OUTn; ++o) acc[o] = 0.0f;

    #pragma unroll
    for (int c = 0; c < Cc; ++c) {
        #pragma unroll
        for (int k = 0; k < KS; ++k) {
            float sv = s[k][c];
            const float* wp = &sW[(c * KS + k) * OUTn];
            #pragma unroll
            for (int o = 0; o < OUTn; ++o) acc[o] = fmaf(sv, wp[o], acc[o]);
        }
    }

    float* op = out + (size_t)tid * OUTn;
    #pragma unroll
    for (int o = 0; o < OUTn; ++o) {
        float r = acc[o] * invdeg;
        op[o] = (r > 0.0f) ? r : 0.0f;
    }
}

extern "C" void kernel_launch(void* const* d_in, const int* in_sizes, int n_in,
                              void* d_out, int out_size, void* d_ws, size_t ws_size,
                              hipStream_t stream) {
    const float* x   = (const float*)d_in[0];
    const float* W   = (const float*)d_in[1];
    const int*   adj = (const int*)d_in[2];
    float*       out = (float*)d_out;

    const int total = Bb * Vv;               // 40000 threads, one per (b,v)
    const int block = 256;
    const int grid  = (total + block - 1) / block;
    nlayer_kernel<<<grid, block, 0, stream>>>(x, W, adj, out);
}